// Round 12
// baseline (463.621 us; speedup 1.0000x reference)
//
#include <hip/hip_runtime.h>
#include <hip/hip_bf16.h>
#include <math.h>

typedef __hip_bfloat16 bf16;
typedef __bf16 bf16x8 __attribute__((ext_vector_type(8)));
typedef float f32x4 __attribute__((ext_vector_type(4)));

#define B_ 8
#define T_ 2048
#define D_ 512
#define H_ 2048

__device__ __forceinline__ float b2f(unsigned short u) {
    return __uint_as_float((unsigned)u << 16);
}
__device__ __forceinline__ float ldf(const float* p, long i) { return p[i]; }
__device__ __forceinline__ float ldf(const bf16* p, long i) {
    return b2f(((const unsigned short*)p)[i]);
}
// tanh-form gelu: v*sigmoid(1.59577(v+0.044715 v^3)); |err| < 1e-3 abs
__device__ __forceinline__ float gelu_f(float v) {
    float a = 1.5957691216057308f * (v + 0.044715f * v * v * v);
    return v / (1.0f + __expf(-a));
}

// Packed (tile-major) layout for GEMM-staged operands:
// tile = 16 rows x 32 cols (1 KB bf16); within-tile offset = (row&15)*32+(col&31);
// tiles row-strip-major then k:
//   off(row,col,K) = ((row>>4)*(K>>5) + (col>>5))*512 + (row&15)*32 + (col&31)
__device__ __forceinline__ long poff(int row, int col, int K) {
    return ((long)(row >> 4) * (K >> 5) + (col >> 5)) * 512 + (row & 15) * 32 + (col & 31);
}

#define GLD16(g, l)                                                          \
    __builtin_amdgcn_global_load_lds(                                        \
        (const __attribute__((address_space(1))) void*)(g),                  \
        (__attribute__((address_space(3))) void*)(l), 16, 0, 0)

__device__ __forceinline__ unsigned lds_off(const void* p) {
    return (unsigned)(unsigned long long)(const __attribute__((address_space(3))) char*)p;
}
// asm ds_read: invisible to the waitcnt legalizer -> no compiler vmcnt(0) pairing
// with outstanding global_load_lds (the R2 failure). Proven-compiling form (R3).
#define DSR(dst, a, OFF)                                                     \
    asm volatile("ds_read_b128 %0, %1 offset:" #OFF : "=v"(dst) : "v"(a))

// ---------------- LayerNorm body over D=512, 256 threads, one row -----------------
template <typename Tin, bool PACKO>
__device__ __forceinline__ void ln_body(const Tin* __restrict__ x,
                                        const float* __restrict__ g,
                                        const float* __restrict__ bb,
                                        bf16* __restrict__ y, int row, int tid,
                                        float* red) {
    long base = (long)row * D_;
    float v0 = ldf(x, base + tid);
    float v1 = ldf(x, base + tid + 256);
    float s = v0 + v1;
#pragma unroll
    for (int off = 32; off > 0; off >>= 1) s += __shfl_down(s, off);
    int lane = tid & 63, wid = tid >> 6;
    if (lane == 0) red[wid] = s;
    __syncthreads();
    float mean = (red[0] + red[1] + red[2] + red[3]) * (1.0f / 512.0f);
    __syncthreads();
    float d0 = v0 - mean, d1 = v1 - mean;
    float vs = d0 * d0 + d1 * d1;
#pragma unroll
    for (int off = 32; off > 0; off >>= 1) vs += __shfl_down(vs, off);
    if (lane == 0) red[wid] = vs;
    __syncthreads();
    float var = (red[0] + red[1] + red[2] + red[3]) * (1.0f / 512.0f);
    float rstd = rsqrtf(var + 1e-5f);
    float o0 = d0 * rstd * g[tid] + bb[tid];
    float o1 = d1 * rstd * g[tid + 256] + bb[tid + 256];
    if (PACKO) {
        y[poff(row, tid, D_)]       = __float2bfloat16(o0);
        y[poff(row, tid + 256, D_)] = __float2bfloat16(o1);
    } else {
        y[base + tid]       = __float2bfloat16(o0);
        y[base + tid + 256] = __float2bfloat16(o1);
    }
}

template <typename Tin, bool PACKO>
__global__ __launch_bounds__(256) void ln_kernel(const Tin* __restrict__ x,
                                                 const float* __restrict__ g,
                                                 const float* __restrict__ bb,
                                                 bf16* __restrict__ y) {
    __shared__ float red[4];
    ln_body<Tin, PACKO>(x, g, bb, y, blockIdx.x, threadIdx.x, red);
}

struct WT6 {
    const float* src[6];
    bf16* dst[6];
    int K[6], N[6];
};

// -------- PREP: one launch = wtrans(6144 blocks) + LN1(16384) + expw(2048) -------
__global__ __launch_bounds__(256) void prep_kernel(WT6 p,
                                                   const float* __restrict__ x,
                                                   const float* __restrict__ ln1g,
                                                   const float* __restrict__ ln1b,
                                                   bf16* __restrict__ h1,
                                                   const float* __restrict__ w,
                                                   bf16* __restrict__ ew) {
    __shared__ float sbuf[64][65];
    int bid = blockIdx.x;
    int tid = threadIdx.x;
    if (bid < 6144) {
        int z = bid >> 10;
        int rem = bid & 1023;
        int n0 = (rem & 31) * 64, k0 = (rem >> 5) * 64;
        int K = p.K[z], N = p.N[z];
        if (n0 >= N || k0 >= K) return;
        const float* W = p.src[z];
        bf16* WT = p.dst[z];
        int tx = tid & 63, ty = tid >> 6;
#pragma unroll
        for (int r = 0; r < 16; ++r) {
            int kl = r * 4 + ty;
            sbuf[kl][tx] = W[(long)(k0 + kl) * N + n0 + tx];
        }
        __syncthreads();
#pragma unroll
        for (int r = 0; r < 16; ++r) {
            int nl = r * 4 + ty;
            WT[poff(n0 + nl, k0 + tx, K)] = __float2bfloat16(sbuf[tx][nl]);
        }
    } else if (bid < 6144 + 16384) {
        ln_body<float, true>(x, ln1g, ln1b, h1, bid - 6144, tid, &sbuf[0][0]);
    } else {
        int row = bid - (6144 + 16384);
        long base = (long)row * T_;
        float v[8];
        float mx = -3.4e38f;
#pragma unroll
        for (int i = 0; i < 8; ++i) {
            v[i] = w[base + tid + i * 256];
            mx = fmaxf(mx, v[i]);
        }
#pragma unroll
        for (int off = 32; off > 0; off >>= 1) mx = fmaxf(mx, __shfl_down(mx, off));
        float* red = &sbuf[0][0];
        if ((tid & 63) == 0) red[tid >> 6] = mx;
        __syncthreads();
        float rmax = fmaxf(fmaxf(red[0], red[1]), fmaxf(red[2], red[3]));
#pragma unroll
        for (int i = 0; i < 8; ++i)
            ew[poff(row, tid + i * 256, T_)] = __float2bfloat16(expf(v[i] - rmax));
    }
}

// ---- max over batch dim of K [B,T,D] -> mk [T*D] (bf16: max of bf16 is exact) ----
__global__ __launch_bounds__(256) void maxk_kernel(const bf16* __restrict__ K,
                                                   bf16* __restrict__ mk) {
    long i = (long)blockIdx.x * 256 + threadIdx.x;
    float m = ldf(K, i);
#pragma unroll
    for (int b = 1; b < B_; ++b) m = fmaxf(m, ldf(K, (long)b * (T_ * D_) + i));
    mk[i] = __float2bfloat16(m);
}

// ------- build kv2T[b][n][t] PACKED with 16-col-group num/den interleave:
//   d -> num_row = (d>>4)*32 + (d&15), den_row = num_row + 16
__global__ __launch_bounds__(256) void kv2t_kernel(const bf16* __restrict__ K_,
                                                   const bf16* __restrict__ V_,
                                                   const bf16* __restrict__ mk,
                                                   bf16* __restrict__ kv2t) {
    __shared__ float sev[64][65];
    __shared__ float se[64][65];
    int tx = threadIdx.x & 63, ty = threadIdx.x >> 6;
    int t0 = blockIdx.x * 64, d0 = blockIdx.y * 64, b = blockIdx.z;
    long ibase = (long)b << 20;
#pragma unroll
    for (int r = 0; r < 16; ++r) {
        int tl = r * 4 + ty;
        long mi = (long)(t0 + tl) * D_ + d0 + tx;
        float e = expf(ldf(K_, ibase + mi) - ldf(mk, mi));
        sev[tl][tx] = e * ldf(V_, ibase + mi);
        se[tl][tx] = e;
    }
    __syncthreads();
    long obase = (long)b << 21;
#pragma unroll
    for (int r = 0; r < 16; ++r) {
        int d = d0 + r * 4 + ty;
        int nrow = ((d >> 4) << 5) + (d & 15);
        kv2t[obase + poff(nrow,      t0 + tx, T_)] = __float2bfloat16(sev[tx][r * 4 + ty]);
        kv2t[obase + poff(nrow + 16, t0 + tx, T_)] = __float2bfloat16(se[tx][r * 4 + ty]);
    }
}

// ---------------- 2-phase MFMA GEMM (proven R6/R11 body) — s2/s5/s6/s8 ------------
template <int BM, int PK>
__global__ __launch_bounds__(256, 4) void mfma_gemm(
    const bf16* __restrict__ A, const bf16* __restrict__ Bt,
    const float* __restrict__ b0, const float* __restrict__ b1,
    const float* __restrict__ b2,
    bf16* __restrict__ Cb, float* __restrict__ Cf,
    const bf16* __restrict__ resb, const float* __restrict__ resf,
    bf16* __restrict__ yq,
    int M, int N, int K, int modes, long bsB, long bsC, long planeStride) {
    constexpr int MI = BM / 32;
    constexpr int NA = BM / 64;
    constexpr int PL = (BM + 128) * 32;
    constexpr bool PA = PK & 1, PB = PK & 2, PCK = PK & 4;
    constexpr long astep = PA ? 512 : 32;
    constexpr long bstep = PB ? 512 : 32;
    __shared__ short Sh[2 * PL];
    int tid = threadIdx.x;
    int lane = tid & 63, wave = tid >> 6;
    int wm = wave & 1, wn = wave >> 1;

    int gx = gridDim.x, gy = gridDim.y;
    long nwg = (long)gx * gy * gridDim.z;
    long o = blockIdx.x + (long)gx * (blockIdx.y + (long)gy * blockIdx.z);
    long wk = (o & 7) * (nwg >> 3) + (o >> 3);
    int bx = (int)(wk % gx);
    long rq = wk / gx;
    int by = (int)(rq % gy);
    int bz = (int)(rq / gy);
    int m0 = by * BM, n0 = bx * 128;

    const short* Ag = (const short*)A;
    const short* Bg = (const short*)Bt + (long)bz * bsB;

    int lr = lane >> 2;
    int le = (lane & 3) * 8;
    const short* ga[NA];
    short* la[NA];
#pragma unroll
    for (int i = 0; i < NA; ++i) {
        int arow = m0 + wave * (BM / 4) + i * 16;
        ga[i] = PA ? Ag + (long)(arow >> 4) * ((long)K << 4) + lane * 8
                   : Ag + (long)(arow + lr) * K + le;
        la[i] = Sh + (wave * (BM / 4) + i * 16) * 32;
    }
    int brow = n0 + wave * 32;
    const short* gb0 = PB ? Bg + (long)(brow >> 4) * ((long)K << 4) + lane * 8
                          : Bg + (long)(brow + lr) * K + le;
    const short* gb1 = PB ? gb0 + ((long)K << 4) : gb0 + 16L * K;
    short* lb0 = Sh + BM * 32 + (wave * 32) * 32;
    short* lb1 = lb0 + 16 * 32;

    f32x4 acc[MI][4];
    f32x4 zz = {0.f, 0.f, 0.f, 0.f};
#pragma unroll
    for (int i = 0; i < MI; ++i)
#pragma unroll
        for (int j = 0; j < 4; ++j) acc[i][j] = zz;

    int fr = lane & 15;
    int fk = (lane >> 4) * 8;
    int rm = wm * (BM / 2);

    auto stage = [&](int kt, int ofs) {
#pragma unroll
        for (int i = 0; i < NA; ++i) GLD16(ga[i] + kt * astep, la[i] + ofs);
        GLD16(gb0 + kt * bstep, lb0 + ofs);
        GLD16(gb1 + kt * bstep, lb1 + ofs);
    };
    auto compute = [&](int ofs) {
        const short* Asb = Sh + ofs;
        const short* Bsb = Sh + ofs + BM * 32;
        bf16x8 af[MI], bv[4];
#pragma unroll
        for (int mi = 0; mi < MI; ++mi)
            af[mi] = *(const bf16x8*)(Asb + (rm + mi * 16 + fr) * 32 + fk);
#pragma unroll
        for (int ni = 0; ni < 4; ++ni)
            bv[ni] = *(const bf16x8*)(Bsb + (wn * 64 + ni * 16 + fr) * 32 + fk);
#pragma unroll
        for (int mi = 0; mi < MI; ++mi)
#pragma unroll
            for (int ni = 0; ni < 4; ++ni)
                acc[mi][ni] = __builtin_amdgcn_mfma_f32_16x16x32_bf16(
                    af[mi], bv[ni], acc[mi][ni], 0, 0, 0);
    };

    int nk = K >> 5;
    stage(0, 0);
    __syncthreads();
    for (int kt = 0; kt < nk; kt += 2) {
        if (kt + 1 < nk) stage(kt + 1, PL);
        compute(0);
        __syncthreads();
        if (kt + 2 < nk) stage(kt + 2, 0);
        compute(PL);
        __syncthreads();
    }

    int cc = lane & 15, cr = (lane >> 4) * 4;
    if (yq) {
        long qb = (long)bz * (long)(T_ * D_);
        int dbase = (n0 + wn * 64) >> 1;
#pragma unroll
        for (int mi = 0; mi < MI; ++mi) {
            int row0 = m0 + rm + mi * 16 + cr;
#pragma unroll
            for (int pp = 0; pp < 2; ++pp) {
                int d = dbase + pp * 16 + cc;
#pragma unroll
                for (int r = 0; r < 4; ++r) {
                    long qi = qb + (long)(row0 + r) * D_ + d;
                    float sq = ldf((const bf16*)yq, qi);
                    yq[qi] = __float2bfloat16(sq * acc[mi][2 * pp][r] /
                                              acc[mi][2 * pp + 1][r]);
                }
            }
        }
        return;
    }
    long cbase = (long)bz * bsC;
#pragma unroll
    for (int mi = 0; mi < MI; ++mi) {
#pragma unroll
        for (int ni = 0; ni < 4; ++ni) {
            int row0 = m0 + rm + mi * 16 + cr;
            int col = n0 + wn * 64 + ni * 16 + cc;
            float bvl;
            long colterm;
            int md, rowstride;
            if (planeStride) {
                int plane = col >> 9;
                int c2 = col & 511;
                const float* bp = (plane == 0) ? b0 : ((plane == 1) ? b1 : b2);
                bvl = bp[c2];
                md = (modes >> (2 * plane)) & 3;
                colterm = (long)plane * planeStride + c2;
                rowstride = 512;
            } else {
                bvl = b0 ? b0[col] : 0.0f;
                md = modes & 3;
                colterm = col;
                rowstride = N;
            }
#pragma unroll
            for (int r = 0; r < 4; ++r) {
                float v = acc[mi][ni][r] + bvl;
                if (md == 1) v = 1.0f / (1.0f + __expf(-v));
                else if (md == 2) v = gelu_f(v);
                long idx;
                if (PCK) idx = cbase + poff(row0 + r, col, N);
                else     idx = cbase + (long)(row0 + r) * rowstride + colterm;
                if (resf) v += resf[idx];
                if (resb) v += ldf(resb, idx);
                if (Cf) Cf[idx] = v;
                else Cb[idx] = __float2bfloat16(v);
            }
        }
    }
}

// ---------------- 8-phase 256x256 MFMA GEMM (T3+T4 template port) -----------------
// 8 waves (2M x 4N), BK=64, 128KB LDS = 2 K-tile buffers (even->buf0, odd->buf1).
// Per K-tile buffer: A [2 half][8 strip][2 kk][16][32] 32KB, B same at +32KB.
// Staging: wave w stages strips {2w,2w+1} of one operand/kk per phase (2 GLD16).
// Phase p (of 8 / iter over tiles {2i,2i+1}): asm ds_read frags || stage-issue ->
// s_barrier -> lgkmcnt(0)+sched_barrier(0) (rule 18) -> setprio(1)+16 MFMA ->
// [vmcnt(4) at odd-phase ends: counted, NEVER 0 in-loop; 2 loads x 2 phases stay
// in flight across barriers] -> s_barrier. Stage targets verified race-free:
// each region written >=1 barrier after its last read; gates ensure the 4 oldest
// loads (the data a phase reads) landed at every even-phase entry.
// EPI 0: Cb packed + bias b0 + gelu (s7).  EPI 1: fused-Yt into yq (s4).
#define PH_BAR  __builtin_amdgcn_s_barrier()
#define PH_LGKM do { asm volatile("s_waitcnt lgkmcnt(0)" ::: "memory");      \
                     __builtin_amdgcn_sched_barrier(0); } while (0)
#define GATE4   asm volatile("s_waitcnt vmcnt(4)" ::: "memory")
#define MMA4(MH)                                                             \
    do {                                                                     \
        __builtin_amdgcn_s_setprio(1);                                       \
        _Pragma("unroll") for (int j = 0; j < 4; ++j) {                      \
            _Pragma("unroll") for (int ni = 0; ni < 4; ++ni)                 \
                acc[(MH) * 4 + j][ni] =                                      \
                    __builtin_amdgcn_mfma_f32_16x16x32_bf16(                 \
                        af[j], bv[ni], acc[(MH) * 4 + j][ni], 0, 0, 0);      \
        }                                                                    \
        __builtin_amdgcn_s_setprio(0);                                       \
    } while (0)

template <int EPI>
__global__ __launch_bounds__(512, 2) void mfma_gemm8(
    const bf16* __restrict__ A, const bf16* __restrict__ Bt,
    const float* __restrict__ b0, bf16* __restrict__ Cb, bf16* __restrict__ yq,
    int M, int N, int K, long bsB) {
    __shared__ short Sh[65536];  // 128 KB
    int tid = threadIdx.x;
    int lane = tid & 63, w = tid >> 6;   // wave 0..7
    int wm = w >> 2, wn = w & 3;
    int fr = lane & 15, fk = (lane >> 4) * 8;

    // 3D chunked XCD swizzle (nwg % 8 == 0 for both users)
    int gx = gridDim.x, gy = gridDim.y;
    long nwg = (long)gx * gy * gridDim.z;
    long o = blockIdx.x + (long)gx * (blockIdx.y + (long)gy * blockIdx.z);
    long wk = (o & 7) * (nwg >> 3) + (o >> 3);
    int bx = (int)(wk % gx);
    long rq = wk / gx;
    int by = (int)(rq % gy);
    int bz = (int)(rq / gy);
    int m0 = by * 256, n0 = bx * 256;

    const short* Ag = (const short*)A;
    const short* Bg = (const short*)Bt + (long)bz * bsB;
    int kt32 = K >> 5;

    // stage pointers: wave w stages strips 2w, 2w+1
    const short* sA0 = Ag + (long)((m0 >> 4) + 2 * w) * kt32 * 512 + lane * 8;
    const short* sA1 = sA0 + (long)kt32 * 512;
    const short* sB0 = Bg + (long)((n0 >> 4) + 2 * w) * kt32 * 512 + lane * 8;
    const short* sB1 = sB0 + (long)kt32 * 512;
    short* dA0 = Sh + ((2 * w) >> 3) * 8192 + ((2 * w) & 7) * 1024;
    short* dA1 = Sh + ((2 * w + 1) >> 3) * 8192 + ((2 * w + 1) & 7) * 1024;
    short* dB0 = dA0 + 16384;
    short* dB1 = dA1 + 16384;
    auto stageA = [&](int t, int kk) {
        long so = (long)(t * 2 + kk) * 512;
        int dof = (t & 1) * 32768 + kk * 512;
        GLD16(sA0 + so, dA0 + dof);
        GLD16(sA1 + so, dA1 + dof);
    };
    auto stageB = [&](int t, int kk) {
        long so = (long)(t * 2 + kk) * 512;
        int dof = (t & 1) * 32768 + kk * 512;
        GLD16(sB0 + so, dB0 + dof);
        GLD16(sB1 + so, dB1 + dof);
    };

    // fragment read bases (bytes): per (buf, kk)
    unsigned aBase = lds_off(Sh) + wm * 16384 + fr * 64 + fk * 2;
    unsigned bBase = lds_off(Sh) + 32768 + (wn >> 1) * 16384 + (wn & 1) * 8192 +
                     fr * 64 + fk * 2;
    unsigned aB00 = aBase, aB01 = aBase + 1024, aB10 = aBase + 65536, aB11 = aBase + 66560;
    unsigned bB00 = bBase, bB01 = bBase + 1024, bB10 = bBase + 65536, bB11 = bBase + 66560;

    f32x4 acc[8][4];
    f32x4 zz = {0.f, 0.f, 0.f, 0.f};
#pragma unroll
    for (int i = 0; i < 8; ++i)
#pragma unroll
        for (int j = 0; j < 4; ++j) acc[i][j] = zz;
    bf16x8 af[4], bv[4];

    auto rdA_lo = [&](unsigned b) {
        DSR(af[0], b, 0); DSR(af[1], b, 2048); DSR(af[2], b, 4096); DSR(af[3], b, 6144);
    };
    auto rdA_hi = [&](unsigned b) {
        DSR(af[0], b, 8192); DSR(af[1], b, 10240); DSR(af[2], b, 12288); DSR(af[3], b, 14336);
    };
    auto rdB = [&](unsigned b) {
        DSR(bv[0], b, 0); DSR(bv[1], b, 2048); DSR(bv[2], b, 4096); DSR(bv[3], b, 6144);
    };

    // prologue: tile 0 (A kk0, B kk0, A kk1, B kk1); gate kk0 landed
    stageA(0, 0); stageB(0, 0); stageA(0, 1); stageB(0, 1);
    asm volatile("s_waitcnt vmcnt(4)" ::: "memory");
    PH_BAR;

    int nkt = K >> 6;
    int niter = nkt >> 1;
#pragma unroll 1
    for (int i = 0; i < niter; ++i) {
        int t1 = 2 * i + 1, t2 = 2 * i + 2;
        bool st2 = t2 < nkt;
        // ph0: tile 2i, kk0, mh0
        rdB(bB00); rdA_lo(aB00);
        stageA(t1, 0);
        PH_BAR; PH_LGKM; MMA4(0); PH_BAR;
        // ph1: kk0, mh1 (bv reused)
        rdA_hi(aB00);
        stageB(t1, 0);
        PH_BAR; PH_LGKM; MMA4(1); GATE4; PH_BAR;
        // ph2: kk1, mh0
        rdB(bB01); rdA_lo(aB01);
        stageA(t1, 1);
        PH_BAR; PH_LGKM; MMA4(0); PH_BAR;
        // ph3: kk1, mh1
        rdA_hi(aB01);
        stageB(t1, 1);
        PH_BAR; PH_LGKM; MMA4(1); GATE4; PH_BAR;
        // ph4: tile 2i+1, kk0, mh0
        rdB(bB10); rdA_lo(aB10);
        if (st2) stageA(t2, 0);
        PH_BAR; PH_LGKM; MMA4(0); PH_BAR;
        // ph5
        rdA_hi(aB10);
        if (st2) stageB(t2, 0);
        PH_BAR; PH_LGKM; MMA4(1); GATE4; PH_BAR;
        // ph6: kk1, mh0
        rdB(bB11); rdA_lo(aB11);
        if (st2) stageA(t2, 1);
        PH_BAR; PH_LGKM; MMA4(0); PH_BAR;
        // ph7
        rdA_hi(aB11);
        if (st2) stageB(t2, 1);
        PH_BAR; PH_LGKM; MMA4(1); GATE4; PH_BAR;
    }

    int cc = lane & 15, cr = (lane >> 4) * 4;
    if (EPI == 1) {
        // fused-Yt: 16-col num/den interleaved B; all lanes active
        long qb = (long)bz * (long)(T_ * D_);
        int dbase = (n0 + wn * 64) >> 1;
#pragma unroll
        for (int mi = 0; mi < 8; ++mi) {
            int row0 = m0 + wm * 128 + mi * 16 + cr;
#pragma unroll
            for (int pp = 0; pp < 2; ++pp) {
                int d = dbase + pp * 16 + cc;
#pragma unroll
                for (int r = 0; r < 4; ++r) {
                    long qi = qb + (long)(row0 + r) * D_ + d;
                    float sq = ldf((const bf16*)yq, qi);
                    yq[qi] = __float2bfloat16(sq * acc[mi][2 * pp][r] /
                                              acc[mi][2 * pp + 1][r]);
                }
            }
        }
    } else {
        // packed C write + bias + gelu
#pragma unroll
        for (int mi = 0; mi < 8; ++mi) {
            int row0 = m0 + wm * 128 + mi * 16 + cr;
#pragma unroll
            for (int ni = 0; ni < 4; ++ni) {
                int col = n0 + wn * 64 + ni * 16 + cc;
                float bvl = b0[col];
#pragma unroll
                for (int r = 0; r < 4; ++r) {
                    float v = gelu_f(acc[mi][ni][r] + bvl);
                    Cb[poff(row0 + r, col, N)] = __float2bfloat16(v);
                }
            }
        }
    }
}

extern "C" void kernel_launch(void* const* d_in, const int* in_sizes, int n_in,
                              void* d_out, int out_size, void* d_ws, size_t ws_size,
                              hipStream_t stream) {
    const float* x    = (const float*)d_in[0];
    const float* ln1g = (const float*)d_in[1];
    const float* ln1b = (const float*)d_in[2];
    const float* Wk   = (const float*)d_in[3];
    const float* bk   = (const float*)d_in[4];
    const float* Wv   = (const float*)d_in[5];
    const float* bv   = (const float*)d_in[6];
    const float* Wq   = (const float*)d_in[7];
    const float* bq   = (const float*)d_in[8];
    const float* w    = (const float*)d_in[9];
    const float* Wo   = (const float*)d_in[10];
    const float* bo   = (const float*)d_in[11];
    const float* ln2g = (const float*)d_in[12];
    const float* ln2b = (const float*)d_in[13];
    const float* W1   = (const float*)d_in[14];
    const float* b1   = (const float*)d_in[15];
    const float* W2   = (const float*)d_in[16];
    const float* b2   = (const float*)d_in[17];
    float* out = (float*)d_out;

    const long S_BTD = (long)B_ * T_ * D_;      // 8,388,608
    const long S_TD  = (long)T_ * D_;           // 1,048,576
    const long S_TT  = (long)T_ * T_;           // 4,194,304
    const long S_B2D = (long)B_ * T_ * 2 * D_;  // 16,777,216
    const long S_DD  = (long)D_ * D_;           // 262,144

    bf16* h1     = (bf16*)d_ws;            // later h2 (both PACKED)
    bf16* outres = h1 + S_BTD;             // linear
    bf16* ew     = outres + S_BTD;         // PACKED
    bf16* KVQ    = ew + S_TT;              // K|V|Q planes (3*S_BTD), linear
    bf16* kv2t   = KVQ + 3 * S_BTD;        // S_B2D, PACKED+interleaved per batch
    bf16* mk     = kv2t + S_B2D;           // S_TD bf16
    bf16* WkT    = mk + 2 * S_TD;          // all weights PACKED
    bf16* WvT    = WkT + S_DD;
    bf16* WqT    = WvT + S_DD;
    bf16* WoT    = WqT + S_DD;
    bf16* W1T    = WoT + S_DD;             // [H,D]
    bf16* W2T    = W1T + (long)D_ * H_;    // [D,H]
    bf16* Kb  = KVQ;
    bf16* Vb  = KVQ + S_BTD;
    bf16* Qb  = KVQ + 2 * S_BTD;           // sigQ linear, then Yt in place (s4)
    bf16* hH  = KVQ;                       // PACKED; spans K|V planes (dead) + more
    bf16* h2  = h1;

    const int M = B_ * T_;  // 16384

    WT6 p;
    p.src[0] = Wk; p.src[1] = Wv; p.src[2] = Wq; p.src[3] = Wo; p.src[4] = W1; p.src[5] = W2;
    p.dst[0] = WkT; p.dst[1] = WvT; p.dst[2] = WqT; p.dst[3] = WoT; p.dst[4] = W1T; p.dst[5] = W2T;
    p.K[0] = p.K[1] = p.K[2] = p.K[3] = 512; p.K[4] = 512; p.K[5] = 2048;
    p.N[0] = p.N[1] = p.N[2] = p.N[3] = 512; p.N[4] = 2048; p.N[5] = 512;

    // 1. PREP: wtrans(6) + LN1 + expw in ONE launch
    prep_kernel<<<6144 + 16384 + 2048, 256, 0, stream>>>(p, x, ln1g, ln1b, h1, w, ew);
    // 2. K|V|sigQ GEMM: planes linear -> Kb,Vb,Qb (sigmoid on Q plane)
    mfma_gemm<128, 3><<<dim3(1536 / 128, M / 128, 1), 256, 0, stream>>>(
        h1, WkT, bk, bv, bq, Kb, nullptr, nullptr, nullptr, nullptr,
        M, 1536, D_, (1 << 4), 0, 0, S_BTD);
    // 3a. mk = max_b K; 3b. kv2t packed + 16-col interleave
    maxk_kernel<<<S_TD / 256, 256, 0, stream>>>(Kb, mk);
    kv2t_kernel<<<dim3(T_ / 64, D_ / 64, B_), 256, 0, stream>>>(Kb, Vb, mk, kv2t);
    // 4. FUSED s4 (8-phase): Yt = sigQ * (ew@expK*V)/(ew@expK), in place into Qb
    mfma_gemm8<1><<<dim3(1024 / 256, T_ / 256, B_), 512, 0, stream>>>(
        ew, kv2t, nullptr, nullptr, Qb, T_, 1024, T_, (long)1024 * T_);
    // 5. out = Yt@Wo + bo + x, C linear + f32 residual
    mfma_gemm<128, 2><<<dim3(D_ / 128, M / 128, 1), 256, 0, stream>>>(
        Qb, WoT, bo, nullptr, nullptr, outres, nullptr, nullptr, x, nullptr,
        M, D_, D_, 0, 0, 0, 0);
    // 6. h2 = LN2(out), packed
    ln_kernel<bf16, true><<<M, 256, 0, stream>>>(outres, ln2g, ln2b, h2);
    // 7. hH = gelu(h2@W1 + b1) (8-phase), C PACKED (= step-8 A)
    mfma_gemm8<0><<<dim3(H_ / 256, M / 256, 1), 512, 0, stream>>>(
        h2, W1T, b1, hH, nullptr, M, H_, D_, 0);
    // 8. y = gelu(hH@W2 + b2) + out -> f32 d_out
    mfma_gemm<128, 3><<<dim3(D_ / 128, M / 128, 1), 256, 0, stream>>>(
        hH, W2T, b2, nullptr, nullptr, nullptr, out, outres, nullptr, nullptr,
        M, D_, H_, 2, 0, 0, 0);
}

// Round 13
// 450.417 us; speedup vs baseline: 1.0293x; 1.0293x over previous
//
#include <hip/hip_runtime.h>
#include <hip/hip_bf16.h>
#include <math.h>

typedef __hip_bfloat16 bf16;
typedef __bf16 bf16x8 __attribute__((ext_vector_type(8)));
typedef float f32x4 __attribute__((ext_vector_type(4)));

#define B_ 8
#define T_ 2048
#define D_ 512
#define H_ 2048

__device__ __forceinline__ float b2f(unsigned short u) {
    return __uint_as_float((unsigned)u << 16);
}
__device__ __forceinline__ float ldf(const float* p, long i) { return p[i]; }
__device__ __forceinline__ float ldf(const bf16* p, long i) {
    return b2f(((const unsigned short*)p)[i]);
}
// tanh-form gelu: v*sigmoid(1.59577(v+0.044715 v^3)); |err| < 1e-3 abs
__device__ __forceinline__ float gelu_f(float v) {
    float a = 1.5957691216057308f * (v + 0.044715f * v * v * v);
    return v / (1.0f + __expf(-a));
}

// Packed (tile-major) layout for GEMM-staged operands, now with baked-in T2
// bank-swizzle (rule #21: global_load_lds writes linearly, so the swizzle is
// applied on the PRODUCER side and mirrored on the ds_read side):
// tile = 16 rows x 32 cols (1 KB bf16); within-tile, the 16B granule index
// (col>>3)&3 is XORed with ((row>>1)&3). A wave's ds_read_b128 at
// row=lane&15, granule=lane>>4 then hits 8 distinct bank-quads per 8-lane
// issue group (2 lanes/bank = free, m136) instead of 4-way conflict.
//   off(row,col,K) = ((row>>4)*(K>>5)+(col>>5))*512
//                  + (row&15)*32 + (((col>>3)&3)^((row>>1)&3))*8 + (col&7)
__device__ __forceinline__ long poff(int row, int col, int K) {
    int sw = ((col >> 3) & 3) ^ ((row >> 1) & 3);
    return ((long)(row >> 4) * (K >> 5) + (col >> 5)) * 512 + (row & 15) * 32 +
           sw * 8 + (col & 7);
}

#define GLD16(g, l)                                                          \
    __builtin_amdgcn_global_load_lds(                                        \
        (const __attribute__((address_space(1))) void*)(g),                  \
        (__attribute__((address_space(3))) void*)(l), 16, 0, 0)

__device__ __forceinline__ unsigned lds_off(const void* p) {
    return (unsigned)(unsigned long long)(const __attribute__((address_space(3))) char*)p;
}
// asm ds_read: invisible to the waitcnt legalizer -> no compiler vmcnt(0) pairing
// with outstanding global_load_lds (the R2 failure). Proven-compiling form (R3).
#define DSR(dst, a, OFF)                                                     \
    asm volatile("ds_read_b128 %0, %1 offset:" #OFF : "=v"(dst) : "v"(a))

// ---------------- LayerNorm body over D=512, 256 threads, one row -----------------
template <typename Tin, bool PACKO>
__device__ __forceinline__ void ln_body(const Tin* __restrict__ x,
                                        const float* __restrict__ g,
                                        const float* __restrict__ bb,
                                        bf16* __restrict__ y, int row, int tid,
                                        float* red) {
    long base = (long)row * D_;
    float v0 = ldf(x, base + tid);
    float v1 = ldf(x, base + tid + 256);
    float s = v0 + v1;
#pragma unroll
    for (int off = 32; off > 0; off >>= 1) s += __shfl_down(s, off);
    int lane = tid & 63, wid = tid >> 6;
    if (lane == 0) red[wid] = s;
    __syncthreads();
    float mean = (red[0] + red[1] + red[2] + red[3]) * (1.0f / 512.0f);
    __syncthreads();
    float d0 = v0 - mean, d1 = v1 - mean;
    float vs = d0 * d0 + d1 * d1;
#pragma unroll
    for (int off = 32; off > 0; off >>= 1) vs += __shfl_down(vs, off);
    if (lane == 0) red[wid] = vs;
    __syncthreads();
    float var = (red[0] + red[1] + red[2] + red[3]) * (1.0f / 512.0f);
    float rstd = rsqrtf(var + 1e-5f);
    float o0 = d0 * rstd * g[tid] + bb[tid];
    float o1 = d1 * rstd * g[tid + 256] + bb[tid + 256];
    if (PACKO) {
        y[poff(row, tid, D_)]       = __float2bfloat16(o0);
        y[poff(row, tid + 256, D_)] = __float2bfloat16(o1);
    } else {
        y[base + tid]       = __float2bfloat16(o0);
        y[base + tid + 256] = __float2bfloat16(o1);
    }
}

template <typename Tin, bool PACKO>
__global__ __launch_bounds__(256) void ln_kernel(const Tin* __restrict__ x,
                                                 const float* __restrict__ g,
                                                 const float* __restrict__ bb,
                                                 bf16* __restrict__ y) {
    __shared__ float red[4];
    ln_body<Tin, PACKO>(x, g, bb, y, blockIdx.x, threadIdx.x, red);
}

struct WT6 {
    const float* src[6];
    bf16* dst[6];
    int K[6], N[6];
};

// -------- PREP: one launch = wtrans(6144 blocks) + LN1(16384) + expw(2048) -------
__global__ __launch_bounds__(256) void prep_kernel(WT6 p,
                                                   const float* __restrict__ x,
                                                   const float* __restrict__ ln1g,
                                                   const float* __restrict__ ln1b,
                                                   bf16* __restrict__ h1,
                                                   const float* __restrict__ w,
                                                   bf16* __restrict__ ew) {
    __shared__ float sbuf[64][65];
    int bid = blockIdx.x;
    int tid = threadIdx.x;
    if (bid < 6144) {
        int z = bid >> 10;
        int rem = bid & 1023;
        int n0 = (rem & 31) * 64, k0 = (rem >> 5) * 64;
        int K = p.K[z], N = p.N[z];
        if (n0 >= N || k0 >= K) return;
        const float* W = p.src[z];
        bf16* WT = p.dst[z];
        int tx = tid & 63, ty = tid >> 6;
#pragma unroll
        for (int r = 0; r < 16; ++r) {
            int kl = r * 4 + ty;
            sbuf[kl][tx] = W[(long)(k0 + kl) * N + n0 + tx];
        }
        __syncthreads();
#pragma unroll
        for (int r = 0; r < 16; ++r) {
            int nl = r * 4 + ty;
            WT[poff(n0 + nl, k0 + tx, K)] = __float2bfloat16(sbuf[tx][nl]);
        }
    } else if (bid < 6144 + 16384) {
        ln_body<float, true>(x, ln1g, ln1b, h1, bid - 6144, tid, &sbuf[0][0]);
    } else {
        int row = bid - (6144 + 16384);
        long base = (long)row * T_;
        float v[8];
        float mx = -3.4e38f;
#pragma unroll
        for (int i = 0; i < 8; ++i) {
            v[i] = w[base + tid + i * 256];
            mx = fmaxf(mx, v[i]);
        }
#pragma unroll
        for (int off = 32; off > 0; off >>= 1) mx = fmaxf(mx, __shfl_down(mx, off));
        float* red = &sbuf[0][0];
        if ((tid & 63) == 0) red[tid >> 6] = mx;
        __syncthreads();
        float rmax = fmaxf(fmaxf(red[0], red[1]), fmaxf(red[2], red[3]));
#pragma unroll
        for (int i = 0; i < 8; ++i)
            ew[poff(row, tid + i * 256, T_)] = __float2bfloat16(expf(v[i] - rmax));
    }
}

// ---- max over batch dim of K [B,T,D] -> mk [T*D] (bf16: max of bf16 is exact) ----
__global__ __launch_bounds__(256) void maxk_kernel(const bf16* __restrict__ K,
                                                   bf16* __restrict__ mk) {
    long i = (long)blockIdx.x * 256 + threadIdx.x;
    float m = ldf(K, i);
#pragma unroll
    for (int b = 1; b < B_; ++b) m = fmaxf(m, ldf(K, (long)b * (T_ * D_) + i));
    mk[i] = __float2bfloat16(m);
}

// ------- build kv2T[b][n][t] PACKED with 16-col-group num/den interleave:
//   d -> num_row = (d>>4)*32 + (d&15), den_row = num_row + 16
__global__ __launch_bounds__(256) void kv2t_kernel(const bf16* __restrict__ K_,
                                                   const bf16* __restrict__ V_,
                                                   const bf16* __restrict__ mk,
                                                   bf16* __restrict__ kv2t) {
    __shared__ float sev[64][65];
    __shared__ float se[64][65];
    int tx = threadIdx.x & 63, ty = threadIdx.x >> 6;
    int t0 = blockIdx.x * 64, d0 = blockIdx.y * 64, b = blockIdx.z;
    long ibase = (long)b << 20;
#pragma unroll
    for (int r = 0; r < 16; ++r) {
        int tl = r * 4 + ty;
        long mi = (long)(t0 + tl) * D_ + d0 + tx;
        float e = expf(ldf(K_, ibase + mi) - ldf(mk, mi));
        sev[tl][tx] = e * ldf(V_, ibase + mi);
        se[tl][tx] = e;
    }
    __syncthreads();
    long obase = (long)b << 21;
#pragma unroll
    for (int r = 0; r < 16; ++r) {
        int d = d0 + r * 4 + ty;
        int nrow = ((d >> 4) << 5) + (d & 15);
        kv2t[obase + poff(nrow,      t0 + tx, T_)] = __float2bfloat16(sev[tx][r * 4 + ty]);
        kv2t[obase + poff(nrow + 16, t0 + tx, T_)] = __float2bfloat16(se[tx][r * 4 + ty]);
    }
}

// ---------------- 2-phase MFMA GEMM (proven R6/R11 body) — s2/s5/s8 ------------
// Packed operands are read with the T2-swizzled granule (matches poff); linear
// operands (s5's A=Qb) keep the unswizzled read. T2 is perf-null at 2-phase per
// the regime-gate, but the shared layout must stay consistent.
template <int BM, int PK>
__global__ __launch_bounds__(256, 4) void mfma_gemm(
    const bf16* __restrict__ A, const bf16* __restrict__ Bt,
    const float* __restrict__ b0, const float* __restrict__ b1,
    const float* __restrict__ b2,
    bf16* __restrict__ Cb, float* __restrict__ Cf,
    const bf16* __restrict__ resb, const float* __restrict__ resf,
    bf16* __restrict__ yq,
    int M, int N, int K, int modes, long bsB, long bsC, long planeStride) {
    constexpr int MI = BM / 32;
    constexpr int NA = BM / 64;
    constexpr int PL = (BM + 128) * 32;
    constexpr bool PA = PK & 1, PB = PK & 2, PCK = PK & 4;
    constexpr long astep = PA ? 512 : 32;
    constexpr long bstep = PB ? 512 : 32;
    __shared__ short Sh[2 * PL];
    int tid = threadIdx.x;
    int lane = tid & 63, wave = tid >> 6;
    int wm = wave & 1, wn = wave >> 1;

    int gx = gridDim.x, gy = gridDim.y;
    long nwg = (long)gx * gy * gridDim.z;
    long o = blockIdx.x + (long)gx * (blockIdx.y + (long)gy * blockIdx.z);
    long wk = (o & 7) * (nwg >> 3) + (o >> 3);
    int bx = (int)(wk % gx);
    long rq = wk / gx;
    int by = (int)(rq % gy);
    int bz = (int)(rq / gy);
    int m0 = by * BM, n0 = bx * 128;

    const short* Ag = (const short*)A;
    const short* Bg = (const short*)Bt + (long)bz * bsB;

    int lr = lane >> 2;
    int le = (lane & 3) * 8;
    const short* ga[NA];
    short* la[NA];
#pragma unroll
    for (int i = 0; i < NA; ++i) {
        int arow = m0 + wave * (BM / 4) + i * 16;
        ga[i] = PA ? Ag + (long)(arow >> 4) * ((long)K << 4) + lane * 8
                   : Ag + (long)(arow + lr) * K + le;
        la[i] = Sh + (wave * (BM / 4) + i * 16) * 32;
    }
    int brow = n0 + wave * 32;
    const short* gb0 = PB ? Bg + (long)(brow >> 4) * ((long)K << 4) + lane * 8
                          : Bg + (long)(brow + lr) * K + le;
    const short* gb1 = PB ? gb0 + ((long)K << 4) : gb0 + 16L * K;
    short* lb0 = Sh + BM * 32 + (wave * 32) * 32;
    short* lb1 = lb0 + 16 * 32;

    f32x4 acc[MI][4];
    f32x4 zz = {0.f, 0.f, 0.f, 0.f};
#pragma unroll
    for (int i = 0; i < MI; ++i)
#pragma unroll
        for (int j = 0; j < 4; ++j) acc[i][j] = zz;

    int fr = lane & 15;
    int gl = lane >> 4;
    int fk  = gl * 8;                          // linear granule (unpacked operand)
    int fks = (gl ^ ((fr >> 1) & 3)) * 8;      // T2-swizzled granule (packed)
    int fkA = PA ? fks : fk;
    int fkB = PB ? fks : fk;
    int rm = wm * (BM / 2);

    auto stage = [&](int kt, int ofs) {
#pragma unroll
        for (int i = 0; i < NA; ++i) GLD16(ga[i] + kt * astep, la[i] + ofs);
        GLD16(gb0 + kt * bstep, lb0 + ofs);
        GLD16(gb1 + kt * bstep, lb1 + ofs);
    };
    auto compute = [&](int ofs) {
        const short* Asb = Sh + ofs;
        const short* Bsb = Sh + ofs + BM * 32;
        bf16x8 af[MI], bv[4];
#pragma unroll
        for (int mi = 0; mi < MI; ++mi)
            af[mi] = *(const bf16x8*)(Asb + (rm + mi * 16 + fr) * 32 + fkA);
#pragma unroll
        for (int ni = 0; ni < 4; ++ni)
            bv[ni] = *(const bf16x8*)(Bsb + (wn * 64 + ni * 16 + fr) * 32 + fkB);
#pragma unroll
        for (int mi = 0; mi < MI; ++mi)
#pragma unroll
            for (int ni = 0; ni < 4; ++ni)
                acc[mi][ni] = __builtin_amdgcn_mfma_f32_16x16x32_bf16(
                    af[mi], bv[ni], acc[mi][ni], 0, 0, 0);
    };

    int nk = K >> 5;
    stage(0, 0);
    __syncthreads();
    for (int kt = 0; kt < nk; kt += 2) {
        if (kt + 1 < nk) stage(kt + 1, PL);
        compute(0);
        __syncthreads();
        if (kt + 2 < nk) stage(kt + 2, 0);
        compute(PL);
        __syncthreads();
    }

    int cc = lane & 15, cr = (lane >> 4) * 4;
    if (yq) {
        long qb = (long)bz * (long)(T_ * D_);
        int dbase = (n0 + wn * 64) >> 1;
#pragma unroll
        for (int mi = 0; mi < MI; ++mi) {
            int row0 = m0 + rm + mi * 16 + cr;
#pragma unroll
            for (int pp = 0; pp < 2; ++pp) {
                int d = dbase + pp * 16 + cc;
#pragma unroll
                for (int r = 0; r < 4; ++r) {
                    long qi = qb + (long)(row0 + r) * D_ + d;
                    float sq = ldf((const bf16*)yq, qi);
                    yq[qi] = __float2bfloat16(sq * acc[mi][2 * pp][r] /
                                              acc[mi][2 * pp + 1][r]);
                }
            }
        }
        return;
    }
    long cbase = (long)bz * bsC;
#pragma unroll
    for (int mi = 0; mi < MI; ++mi) {
#pragma unroll
        for (int ni = 0; ni < 4; ++ni) {
            int row0 = m0 + rm + mi * 16 + cr;
            int col = n0 + wn * 64 + ni * 16 + cc;
            float bvl;
            long colterm;
            int md, rowstride;
            if (planeStride) {
                int plane = col >> 9;
                int c2 = col & 511;
                const float* bp = (plane == 0) ? b0 : ((plane == 1) ? b1 : b2);
                bvl = bp[c2];
                md = (modes >> (2 * plane)) & 3;
                colterm = (long)plane * planeStride + c2;
                rowstride = 512;
            } else {
                bvl = b0 ? b0[col] : 0.0f;
                md = modes & 3;
                colterm = col;
                rowstride = N;
            }
#pragma unroll
            for (int r = 0; r < 4; ++r) {
                float v = acc[mi][ni][r] + bvl;
                if (md == 1) v = 1.0f / (1.0f + __expf(-v));
                else if (md == 2) v = gelu_f(v);
                long idx;
                if (PCK) idx = cbase + poff(row0 + r, col, N);
                else     idx = cbase + (long)(row0 + r) * rowstride + colterm;
                if (resf) v += resf[idx];
                if (resb) v += ldf(resb, idx);
                if (Cf) Cf[idx] = v;
                else Cb[idx] = __float2bfloat16(v);
            }
        }
    }
}

// ---------------- 8-phase 256x256 MFMA GEMM (T3+T4 template port) -----------------
// 8 waves (2M x 4N), BK=64, 128KB LDS = 2 K-tile buffers (even->buf0, odd->buf1).
// Staging: wave w stages strips {2w,2w+1} of one operand/kk per phase (2 GLD16).
// Phase: asm ds_read frags || stage-issue -> s_barrier -> lgkmcnt(0)+sched_barrier
// (rule 18) -> setprio(1)+16 MFMA -> [vmcnt(4) at odd-phase ends: counted, never 0
// in-loop] -> s_barrier. T2 swizzle: packed layout is inverse-swizzled at the
// producer (poff), LDS dest linear, read granule XORed here (gsw) — conflict-free.
// EPI 0: Cb packed + bias b0 + gelu (s7).  EPI 1: fused-Yt into yq (s4).
#define PH_BAR  __builtin_amdgcn_s_barrier()
#define PH_LGKM do { asm volatile("s_waitcnt lgkmcnt(0)" ::: "memory");      \
                     __builtin_amdgcn_sched_barrier(0); } while (0)
#define GATE4   asm volatile("s_waitcnt vmcnt(4)" ::: "memory")
#define MMA4(MH)                                                             \
    do {                                                                     \
        __builtin_amdgcn_s_setprio(1);                                       \
        _Pragma("unroll") for (int j = 0; j < 4; ++j) {                      \
            _Pragma("unroll") for (int ni = 0; ni < 4; ++ni)                 \
                acc[(MH) * 4 + j][ni] =                                      \
                    __builtin_amdgcn_mfma_f32_16x16x32_bf16(                 \
                        af[j], bv[ni], acc[(MH) * 4 + j][ni], 0, 0, 0);      \
        }                                                                    \
        __builtin_amdgcn_s_setprio(0);                                       \
    } while (0)

template <int EPI>
__global__ __launch_bounds__(512, 2) void mfma_gemm8(
    const bf16* __restrict__ A, const bf16* __restrict__ Bt,
    const float* __restrict__ b0, bf16* __restrict__ Cb, bf16* __restrict__ yq,
    int M, int N, int K, long bsB) {
    __shared__ short Sh[65536];  // 128 KB
    int tid = threadIdx.x;
    int lane = tid & 63, w = tid >> 6;   // wave 0..7
    int wm = w >> 2, wn = w & 3;
    int fr = lane & 15;

    // 3D chunked XCD swizzle (nwg % 8 == 0 for both users)
    int gx = gridDim.x, gy = gridDim.y;
    long nwg = (long)gx * gy * gridDim.z;
    long o = blockIdx.x + (long)gx * (blockIdx.y + (long)gy * blockIdx.z);
    long wk = (o & 7) * (nwg >> 3) + (o >> 3);
    int bx = (int)(wk % gx);
    long rq = wk / gx;
    int by = (int)(rq % gy);
    int bz = (int)(rq / gy);
    int m0 = by * 256, n0 = bx * 256;

    const short* Ag = (const short*)A;
    const short* Bg = (const short*)Bt + (long)bz * bsB;
    int kt32 = K >> 5;

    // stage pointers: wave w stages strips 2w, 2w+1
    const short* sA0 = Ag + (long)((m0 >> 4) + 2 * w) * kt32 * 512 + lane * 8;
    const short* sA1 = sA0 + (long)kt32 * 512;
    const short* sB0 = Bg + (long)((n0 >> 4) + 2 * w) * kt32 * 512 + lane * 8;
    const short* sB1 = sB0 + (long)kt32 * 512;
    short* dA0 = Sh + ((2 * w) >> 3) * 8192 + ((2 * w) & 7) * 1024;
    short* dA1 = Sh + ((2 * w + 1) >> 3) * 8192 + ((2 * w + 1) & 7) * 1024;
    short* dB0 = dA0 + 16384;
    short* dB1 = dA1 + 16384;
    auto stageA = [&](int t, int kk) {
        long so = (long)(t * 2 + kk) * 512;
        int dof = (t & 1) * 32768 + kk * 512;
        GLD16(sA0 + so, dA0 + dof);
        GLD16(sA1 + so, dA1 + dof);
    };
    auto stageB = [&](int t, int kk) {
        long so = (long)(t * 2 + kk) * 512;
        int dof = (t & 1) * 32768 + kk * 512;
        GLD16(sB0 + so, dB0 + dof);
        GLD16(sB1 + so, dB1 + dof);
    };

    // fragment read bases (bytes): T2-swizzled granule (matches poff producer)
    int gsw = ((lane >> 4) ^ ((fr >> 1) & 3)) * 16;
    unsigned aBase = lds_off(Sh) + wm * 16384 + fr * 64 + gsw;
    unsigned bBase = lds_off(Sh) + 32768 + (wn >> 1) * 16384 + (wn & 1) * 8192 +
                     fr * 64 + gsw;
    unsigned aB00 = aBase, aB01 = aBase + 1024, aB10 = aBase + 65536, aB11 = aBase + 66560;
    unsigned bB00 = bBase, bB01 = bBase + 1024, bB10 = bBase + 65536, bB11 = bBase + 66560;

    f32x4 acc[8][4];
    f32x4 zz = {0.f, 0.f, 0.f, 0.f};
#pragma unroll
    for (int i = 0; i < 8; ++i)
#pragma unroll
        for (int j = 0; j < 4; ++j) acc[i][j] = zz;
    bf16x8 af[4], bv[4];

    auto rdA_lo = [&](unsigned b) {
        DSR(af[0], b, 0); DSR(af[1], b, 2048); DSR(af[2], b, 4096); DSR(af[3], b, 6144);
    };
    auto rdA_hi = [&](unsigned b) {
        DSR(af[0], b, 8192); DSR(af[1], b, 10240); DSR(af[2], b, 12288); DSR(af[3], b, 14336);
    };
    auto rdB = [&](unsigned b) {
        DSR(bv[0], b, 0); DSR(bv[1], b, 2048); DSR(bv[2], b, 4096); DSR(bv[3], b, 6144);
    };

    // prologue: tile 0 (A kk0, B kk0, A kk1, B kk1); gate kk0 landed
    stageA(0, 0); stageB(0, 0); stageA(0, 1); stageB(0, 1);
    asm volatile("s_waitcnt vmcnt(4)" ::: "memory");
    PH_BAR;

    int nkt = K >> 6;
    int niter = nkt >> 1;
#pragma unroll 1
    for (int i = 0; i < niter; ++i) {
        int t1 = 2 * i + 1, t2 = 2 * i + 2;
        bool st2 = t2 < nkt;
        // ph0: tile 2i, kk0, mh0
        rdB(bB00); rdA_lo(aB00);
        stageA(t1, 0);
        PH_BAR; PH_LGKM; MMA4(0); PH_BAR;
        // ph1: kk0, mh1 (bv reused)
        rdA_hi(aB00);
        stageB(t1, 0);
        PH_BAR; PH_LGKM; MMA4(1); GATE4; PH_BAR;
        // ph2: kk1, mh0
        rdB(bB01); rdA_lo(aB01);
        stageA(t1, 1);
        PH_BAR; PH_LGKM; MMA4(0); PH_BAR;
        // ph3: kk1, mh1
        rdA_hi(aB01);
        stageB(t1, 1);
        PH_BAR; PH_LGKM; MMA4(1); GATE4; PH_BAR;
        // ph4: tile 2i+1, kk0, mh0
        rdB(bB10); rdA_lo(aB10);
        if (st2) stageA(t2, 0);
        PH_BAR; PH_LGKM; MMA4(0); PH_BAR;
        // ph5
        rdA_hi(aB10);
        if (st2) stageB(t2, 0);
        PH_BAR; PH_LGKM; MMA4(1); GATE4; PH_BAR;
        // ph6: kk1, mh0
        rdB(bB11); rdA_lo(aB11);
        if (st2) stageA(t2, 1);
        PH_BAR; PH_LGKM; MMA4(0); PH_BAR;
        // ph7
        rdA_hi(aB11);
        if (st2) stageB(t2, 1);
        PH_BAR; PH_LGKM; MMA4(1); GATE4; PH_BAR;
    }

    int cc = lane & 15, cr = (lane >> 4) * 4;
    if (EPI == 1) {
        // fused-Yt: 16-col num/den interleaved B; all lanes active
        long qb = (long)bz * (long)(T_ * D_);
        int dbase = (n0 + wn * 64) >> 1;
#pragma unroll
        for (int mi = 0; mi < 8; ++mi) {
            int row0 = m0 + wm * 128 + mi * 16 + cr;
#pragma unroll
            for (int pp = 0; pp < 2; ++pp) {
                int d = dbase + pp * 16 + cc;
#pragma unroll
                for (int r = 0; r < 4; ++r) {
                    long qi = qb + (long)(row0 + r) * D_ + d;
                    float sq = ldf((const bf16*)yq, qi);
                    yq[qi] = __float2bfloat16(sq * acc[mi][2 * pp][r] /
                                              acc[mi][2 * pp + 1][r]);
                }
            }
        }
    } else {
        // packed C write + bias + gelu
#pragma unroll
        for (int mi = 0; mi < 8; ++mi) {
            int row0 = m0 + wm * 128 + mi * 16 + cr;
#pragma unroll
            for (int ni = 0; ni < 4; ++ni) {
                int col = n0 + wn * 64 + ni * 16 + cc;
                float bvl = b0[col];
#pragma unroll
                for (int r = 0; r < 4; ++r) {
                    float v = gelu_f(acc[mi][ni][r] + bvl);
                    Cb[poff(row0 + r, col, N)] = __float2bfloat16(v);
                }
            }
        }
    }
}

extern "C" void kernel_launch(void* const* d_in, const int* in_sizes, int n_in,
                              void* d_out, int out_size, void* d_ws, size_t ws_size,
                              hipStream_t stream) {
    const float* x    = (const float*)d_in[0];
    const float* ln1g = (const float*)d_in[1];
    const float* ln1b = (const float*)d_in[2];
    const float* Wk   = (const float*)d_in[3];
    const float* bk   = (const float*)d_in[4];
    const float* Wv   = (const float*)d_in[5];
    const float* bv   = (const float*)d_in[6];
    const float* Wq   = (const float*)d_in[7];
    const float* bq   = (const float*)d_in[8];
    const float* w    = (const float*)d_in[9];
    const float* Wo   = (const float*)d_in[10];
    const float* bo   = (const float*)d_in[11];
    const float* ln2g = (const float*)d_in[12];
    const float* ln2b = (const float*)d_in[13];
    const float* W1   = (const float*)d_in[14];
    const float* b1   = (const float*)d_in[15];
    const float* W2   = (const float*)d_in[16];
    const float* b2   = (const float*)d_in[17];
    float* out = (float*)d_out;

    const long S_BTD = (long)B_ * T_ * D_;      // 8,388,608
    const long S_TD  = (long)T_ * D_;           // 1,048,576
    const long S_TT  = (long)T_ * T_;           // 4,194,304
    const long S_B2D = (long)B_ * T_ * 2 * D_;  // 16,777,216
    const long S_DD  = (long)D_ * D_;           // 262,144

    bf16* h1     = (bf16*)d_ws;            // later h2 (both PACKED)
    bf16* outres = h1 + S_BTD;             // linear
    bf16* ew     = outres + S_BTD;         // PACKED
    bf16* KVQ    = ew + S_TT;              // K|V|Q planes (3*S_BTD), linear
    bf16* kv2t   = KVQ + 3 * S_BTD;        // S_B2D, PACKED+interleaved per batch
    bf16* mk     = kv2t + S_B2D;           // S_TD bf16
    bf16* WkT    = mk + 2 * S_TD;          // all weights PACKED
    bf16* WvT    = WkT + S_DD;
    bf16* WqT    = WvT + S_DD;
    bf16* WoT    = WqT + S_DD;
    bf16* W1T    = WoT + S_DD;             // [H,D]
    bf16* W2T    = W1T + (long)D_ * H_;    // [D,H]
    bf16* Kb  = KVQ;
    bf16* Vb  = KVQ + S_BTD;
    bf16* Qb  = KVQ + 2 * S_BTD;           // sigQ linear, then Yt in place (s4)
    bf16* hH  = KVQ;                       // PACKED; spans K|V planes (dead) + more
    bf16* h2  = h1;

    const int M = B_ * T_;  // 16384

    WT6 p;
    p.src[0] = Wk; p.src[1] = Wv; p.src[2] = Wq; p.src[3] = Wo; p.src[4] = W1; p.src[5] = W2;
    p.dst[0] = WkT; p.dst[1] = WvT; p.dst[2] = WqT; p.dst[3] = WoT; p.dst[4] = W1T; p.dst[5] = W2T;
    p.K[0] = p.K[1] = p.K[2] = p.K[3] = 512; p.K[4] = 512; p.K[5] = 2048;
    p.N[0] = p.N[1] = p.N[2] = p.N[3] = 512; p.N[4] = 2048; p.N[5] = 512;

    // 1. PREP: wtrans(6) + LN1 + expw in ONE launch
    prep_kernel<<<6144 + 16384 + 2048, 256, 0, stream>>>(p, x, ln1g, ln1b, h1, w, ew);
    // 2. K|V|sigQ GEMM: planes linear -> Kb,Vb,Qb (sigmoid on Q plane)
    mfma_gemm<128, 3><<<dim3(1536 / 128, M / 128, 1), 256, 0, stream>>>(
        h1, WkT, bk, bv, bq, Kb, nullptr, nullptr, nullptr, nullptr,
        M, 1536, D_, (1 << 4), 0, 0, S_BTD);
    // 3a. mk = max_b K; 3b. kv2t packed + 16-col interleave
    maxk_kernel<<<S_TD / 256, 256, 0, stream>>>(Kb, mk);
    kv2t_kernel<<<dim3(T_ / 64, D_ / 64, B_), 256, 0, stream>>>(Kb, Vb, mk, kv2t);
    // 4. FUSED s4 (8-phase): Yt = sigQ * (ew@expK*V)/(ew@expK), in place into Qb
    mfma_gemm8<1><<<dim3(1024 / 256, T_ / 256, B_), 512, 0, stream>>>(
        ew, kv2t, nullptr, nullptr, Qb, T_, 1024, T_, (long)1024 * T_);
    // 5. out = Yt@Wo + bo + x, C linear + f32 residual
    mfma_gemm<128, 2><<<dim3(D_ / 128, M / 128, 1), 256, 0, stream>>>(
        Qb, WoT, bo, nullptr, nullptr, outres, nullptr, nullptr, x, nullptr,
        M, D_, D_, 0, 0, 0, 0);
    // 6. h2 = LN2(out), packed
    ln_kernel<bf16, true><<<M, 256, 0, stream>>>(outres, ln2g, ln2b, h2);
    // 7. hH = gelu(h2@W1 + b1) (8-phase), C PACKED (= step-8 A)
    mfma_gemm8<0><<<dim3(H_ / 256, M / 256, 1), 512, 0, stream>>>(
        h2, W1T, b1, hH, nullptr, M, H_, D_, 0);
    // 8. y = gelu(hH@W2 + b2) + out -> f32 d_out
    mfma_gemm<128, 3><<<dim3(D_ / 128, M / 128, 1), 256, 0, stream>>>(
        hH, W2T, b2, nullptr, nullptr, nullptr, out, outres, nullptr, nullptr,
        M, D_, H_, 2, 0, 0, 0);
}

// Round 14
// 441.820 us; speedup vs baseline: 1.0493x; 1.0195x over previous
//
#include <hip/hip_runtime.h>
#include <hip/hip_bf16.h>
#include <math.h>

typedef __hip_bfloat16 bf16;
typedef __bf16 bf16x8 __attribute__((ext_vector_type(8)));
typedef float f32x4 __attribute__((ext_vector_type(4)));

#define B_ 8
#define T_ 2048
#define D_ 512
#define H_ 2048

__device__ __forceinline__ float b2f(unsigned short u) {
    return __uint_as_float((unsigned)u << 16);
}
__device__ __forceinline__ float ldf(const float* p, long i) { return p[i]; }
__device__ __forceinline__ float ldf(const bf16* p, long i) {
    return b2f(((const unsigned short*)p)[i]);
}
// tanh-form gelu: v*sigmoid(1.59577(v+0.044715 v^3)); |err| < 1e-3 abs
__device__ __forceinline__ float gelu_f(float v) {
    float a = 1.5957691216057308f * (v + 0.044715f * v * v * v);
    return v / (1.0f + __expf(-a));
}

// Packed (tile-major) layout for GEMM-staged operands, with baked-in T2
// bank-swizzle (rule #21: global_load_lds writes linearly, so the swizzle is
// applied on the PRODUCER side and mirrored on the ds_read side):
// tile = 16 rows x 32 cols (1 KB bf16); within-tile, the 16B granule index
// (col>>3)&3 is XORed with ((row>>1)&3). A wave's ds_read_b128 at
// row=lane&15, granule=lane>>4 then hits 8 distinct bank-quads per 8-lane
// issue group (2 lanes/bank = free, m136). [R13: conflicts 6.3M -> 0]
__device__ __forceinline__ long poff(int row, int col, int K) {
    int sw = ((col >> 3) & 3) ^ ((row >> 1) & 3);
    return ((long)(row >> 4) * (K >> 5) + (col >> 5)) * 512 + (row & 15) * 32 +
           sw * 8 + (col & 7);
}

#define GLD16(g, l)                                                          \
    __builtin_amdgcn_global_load_lds(                                        \
        (const __attribute__((address_space(1))) void*)(g),                  \
        (__attribute__((address_space(3))) void*)(l), 16, 0, 0)

__device__ __forceinline__ unsigned lds_off(const void* p) {
    return (unsigned)(unsigned long long)(const __attribute__((address_space(3))) char*)p;
}
// asm ds_read: invisible to the waitcnt legalizer -> no compiler vmcnt(0) pairing
// with outstanding global_load_lds (the R2 failure). Proven-compiling form (R3).
#define DSR(dst, a, OFF)                                                     \
    asm volatile("ds_read_b128 %0, %1 offset:" #OFF : "=v"(dst) : "v"(a))

// ---------------- LayerNorm body over D=512, 256 threads, one row -----------------
template <typename Tin, bool PACKO>
__device__ __forceinline__ void ln_body(const Tin* __restrict__ x,
                                        const float* __restrict__ g,
                                        const float* __restrict__ bb,
                                        bf16* __restrict__ y, int row, int tid,
                                        float* red) {
    long base = (long)row * D_;
    float v0 = ldf(x, base + tid);
    float v1 = ldf(x, base + tid + 256);
    float s = v0 + v1;
#pragma unroll
    for (int off = 32; off > 0; off >>= 1) s += __shfl_down(s, off);
    int lane = tid & 63, wid = tid >> 6;
    if (lane == 0) red[wid] = s;
    __syncthreads();
    float mean = (red[0] + red[1] + red[2] + red[3]) * (1.0f / 512.0f);
    __syncthreads();
    float d0 = v0 - mean, d1 = v1 - mean;
    float vs = d0 * d0 + d1 * d1;
#pragma unroll
    for (int off = 32; off > 0; off >>= 1) vs += __shfl_down(vs, off);
    if (lane == 0) red[wid] = vs;
    __syncthreads();
    float var = (red[0] + red[1] + red[2] + red[3]) * (1.0f / 512.0f);
    float rstd = rsqrtf(var + 1e-5f);
    float o0 = d0 * rstd * g[tid] + bb[tid];
    float o1 = d1 * rstd * g[tid + 256] + bb[tid + 256];
    if (PACKO) {
        y[poff(row, tid, D_)]       = __float2bfloat16(o0);
        y[poff(row, tid + 256, D_)] = __float2bfloat16(o1);
    } else {
        y[base + tid]       = __float2bfloat16(o0);
        y[base + tid + 256] = __float2bfloat16(o1);
    }
}

template <typename Tin, bool PACKO>
__global__ __launch_bounds__(256) void ln_kernel(const Tin* __restrict__ x,
                                                 const float* __restrict__ g,
                                                 const float* __restrict__ bb,
                                                 bf16* __restrict__ y) {
    __shared__ float red[4];
    ln_body<Tin, PACKO>(x, g, bb, y, blockIdx.x, threadIdx.x, red);
}

struct WT6 {
    const float* src[6];
    bf16* dst[6];
    int K[6], N[6];
};

// -------- PREP: one launch = wtrans(6144 blocks) + LN1(16384) + expw(2048) -------
__global__ __launch_bounds__(256) void prep_kernel(WT6 p,
                                                   const float* __restrict__ x,
                                                   const float* __restrict__ ln1g,
                                                   const float* __restrict__ ln1b,
                                                   bf16* __restrict__ h1,
                                                   const float* __restrict__ w,
                                                   bf16* __restrict__ ew) {
    __shared__ float sbuf[64][65];
    int bid = blockIdx.x;
    int tid = threadIdx.x;
    if (bid < 6144) {
        int z = bid >> 10;
        int rem = bid & 1023;
        int n0 = (rem & 31) * 64, k0 = (rem >> 5) * 64;
        int K = p.K[z], N = p.N[z];
        if (n0 >= N || k0 >= K) return;
        const float* W = p.src[z];
        bf16* WT = p.dst[z];
        int tx = tid & 63, ty = tid >> 6;
#pragma unroll
        for (int r = 0; r < 16; ++r) {
            int kl = r * 4 + ty;
            sbuf[kl][tx] = W[(long)(k0 + kl) * N + n0 + tx];
        }
        __syncthreads();
#pragma unroll
        for (int r = 0; r < 16; ++r) {
            int nl = r * 4 + ty;
            WT[poff(n0 + nl, k0 + tx, K)] = __float2bfloat16(sbuf[tx][nl]);
        }
    } else if (bid < 6144 + 16384) {
        ln_body<float, true>(x, ln1g, ln1b, h1, bid - 6144, tid, &sbuf[0][0]);
    } else {
        int row = bid - (6144 + 16384);
        long base = (long)row * T_;
        float v[8];
        float mx = -3.4e38f;
#pragma unroll
        for (int i = 0; i < 8; ++i) {
            v[i] = w[base + tid + i * 256];
            mx = fmaxf(mx, v[i]);
        }
#pragma unroll
        for (int off = 32; off > 0; off >>= 1) mx = fmaxf(mx, __shfl_down(mx, off));
        float* red = &sbuf[0][0];
        if ((tid & 63) == 0) red[tid >> 6] = mx;
        __syncthreads();
        float rmax = fmaxf(fmaxf(red[0], red[1]), fmaxf(red[2], red[3]));
#pragma unroll
        for (int i = 0; i < 8; ++i)
            ew[poff(row, tid + i * 256, T_)] = __float2bfloat16(expf(v[i] - rmax));
    }
}

// ---- max over batch dim of K [B,T,D] -> mk [T*D] (bf16: max of bf16 is exact) ----
__global__ __launch_bounds__(256) void maxk_kernel(const bf16* __restrict__ K,
                                                   bf16* __restrict__ mk) {
    long i = (long)blockIdx.x * 256 + threadIdx.x;
    float m = ldf(K, i);
#pragma unroll
    for (int b = 1; b < B_; ++b) m = fmaxf(m, ldf(K, (long)b * (T_ * D_) + i));
    mk[i] = __float2bfloat16(m);
}

// ------- build kv2T[b][n][t] PACKED with 16-col-group num/den interleave:
//   d -> num_row = (d>>4)*32 + (d&15), den_row = num_row + 16
__global__ __launch_bounds__(256) void kv2t_kernel(const bf16* __restrict__ K_,
                                                   const bf16* __restrict__ V_,
                                                   const bf16* __restrict__ mk,
                                                   bf16* __restrict__ kv2t) {
    __shared__ float sev[64][65];
    __shared__ float se[64][65];
    int tx = threadIdx.x & 63, ty = threadIdx.x >> 6;
    int t0 = blockIdx.x * 64, d0 = blockIdx.y * 64, b = blockIdx.z;
    long ibase = (long)b << 20;
#pragma unroll
    for (int r = 0; r < 16; ++r) {
        int tl = r * 4 + ty;
        long mi = (long)(t0 + tl) * D_ + d0 + tx;
        float e = expf(ldf(K_, ibase + mi) - ldf(mk, mi));
        sev[tl][tx] = e * ldf(V_, ibase + mi);
        se[tl][tx] = e;
    }
    __syncthreads();
    long obase = (long)b << 21;
#pragma unroll
    for (int r = 0; r < 16; ++r) {
        int d = d0 + r * 4 + ty;
        int nrow = ((d >> 4) << 5) + (d & 15);
        kv2t[obase + poff(nrow,      t0 + tx, T_)] = __float2bfloat16(sev[tx][r * 4 + ty]);
        kv2t[obase + poff(nrow + 16, t0 + tx, T_)] = __float2bfloat16(se[tx][r * 4 + ty]);
    }
}

// ---------------- 2-phase MFMA GEMM (proven R6/R11 body) — s5/s8 ------------------
template <int BM, int PK>
__global__ __launch_bounds__(256, 4) void mfma_gemm(
    const bf16* __restrict__ A, const bf16* __restrict__ Bt,
    const float* __restrict__ b0, const float* __restrict__ b1,
    const float* __restrict__ b2,
    bf16* __restrict__ Cb, float* __restrict__ Cf,
    const bf16* __restrict__ resb, const float* __restrict__ resf,
    bf16* __restrict__ yq,
    int M, int N, int K, int modes, long bsB, long bsC, long planeStride) {
    constexpr int MI = BM / 32;
    constexpr int NA = BM / 64;
    constexpr int PL = (BM + 128) * 32;
    constexpr bool PA = PK & 1, PB = PK & 2, PCK = PK & 4;
    constexpr long astep = PA ? 512 : 32;
    constexpr long bstep = PB ? 512 : 32;
    __shared__ short Sh[2 * PL];
    int tid = threadIdx.x;
    int lane = tid & 63, wave = tid >> 6;
    int wm = wave & 1, wn = wave >> 1;

    int gx = gridDim.x, gy = gridDim.y;
    long nwg = (long)gx * gy * gridDim.z;
    long o = blockIdx.x + (long)gx * (blockIdx.y + (long)gy * blockIdx.z);
    long wk = (o & 7) * (nwg >> 3) + (o >> 3);
    int bx = (int)(wk % gx);
    long rq = wk / gx;
    int by = (int)(rq % gy);
    int bz = (int)(rq / gy);
    int m0 = by * BM, n0 = bx * 128;

    const short* Ag = (const short*)A;
    const short* Bg = (const short*)Bt + (long)bz * bsB;

    int lr = lane >> 2;
    int le = (lane & 3) * 8;
    const short* ga[NA];
    short* la[NA];
#pragma unroll
    for (int i = 0; i < NA; ++i) {
        int arow = m0 + wave * (BM / 4) + i * 16;
        ga[i] = PA ? Ag + (long)(arow >> 4) * ((long)K << 4) + lane * 8
                   : Ag + (long)(arow + lr) * K + le;
        la[i] = Sh + (wave * (BM / 4) + i * 16) * 32;
    }
    int brow = n0 + wave * 32;
    const short* gb0 = PB ? Bg + (long)(brow >> 4) * ((long)K << 4) + lane * 8
                          : Bg + (long)(brow + lr) * K + le;
    const short* gb1 = PB ? gb0 + ((long)K << 4) : gb0 + 16L * K;
    short* lb0 = Sh + BM * 32 + (wave * 32) * 32;
    short* lb1 = lb0 + 16 * 32;

    f32x4 acc[MI][4];
    f32x4 zz = {0.f, 0.f, 0.f, 0.f};
#pragma unroll
    for (int i = 0; i < MI; ++i)
#pragma unroll
        for (int j = 0; j < 4; ++j) acc[i][j] = zz;

    int fr = lane & 15;
    int gl = lane >> 4;
    int fk  = gl * 8;                          // linear granule (unpacked operand)
    int fks = (gl ^ ((fr >> 1) & 3)) * 8;      // T2-swizzled granule (packed)
    int fkA = PA ? fks : fk;
    int fkB = PB ? fks : fk;
    int rm = wm * (BM / 2);

    auto stage = [&](int kt, int ofs) {
#pragma unroll
        for (int i = 0; i < NA; ++i) GLD16(ga[i] + kt * astep, la[i] + ofs);
        GLD16(gb0 + kt * bstep, lb0 + ofs);
        GLD16(gb1 + kt * bstep, lb1 + ofs);
    };
    auto compute = [&](int ofs) {
        const short* Asb = Sh + ofs;
        const short* Bsb = Sh + ofs + BM * 32;
        bf16x8 af[MI], bv[4];
#pragma unroll
        for (int mi = 0; mi < MI; ++mi)
            af[mi] = *(const bf16x8*)(Asb + (rm + mi * 16 + fr) * 32 + fkA);
#pragma unroll
        for (int ni = 0; ni < 4; ++ni)
            bv[ni] = *(const bf16x8*)(Bsb + (wn * 64 + ni * 16 + fr) * 32 + fkB);
#pragma unroll
        for (int mi = 0; mi < MI; ++mi)
#pragma unroll
            for (int ni = 0; ni < 4; ++ni)
                acc[mi][ni] = __builtin_amdgcn_mfma_f32_16x16x32_bf16(
                    af[mi], bv[ni], acc[mi][ni], 0, 0, 0);
    };

    int nk = K >> 5;
    stage(0, 0);
    __syncthreads();
    for (int kt = 0; kt < nk; kt += 2) {
        if (kt + 1 < nk) stage(kt + 1, PL);
        compute(0);
        __syncthreads();
        if (kt + 2 < nk) stage(kt + 2, 0);
        compute(PL);
        __syncthreads();
    }

    int cc = lane & 15, cr = (lane >> 4) * 4;
    if (yq) {
        long qb = (long)bz * (long)(T_ * D_);
        int dbase = (n0 + wn * 64) >> 1;
#pragma unroll
        for (int mi = 0; mi < MI; ++mi) {
            int row0 = m0 + rm + mi * 16 + cr;
#pragma unroll
            for (int pp = 0; pp < 2; ++pp) {
                int d = dbase + pp * 16 + cc;
#pragma unroll
                for (int r = 0; r < 4; ++r) {
                    long qi = qb + (long)(row0 + r) * D_ + d;
                    float sq = ldf((const bf16*)yq, qi);
                    yq[qi] = __float2bfloat16(sq * acc[mi][2 * pp][r] /
                                              acc[mi][2 * pp + 1][r]);
                }
            }
        }
        return;
    }
    long cbase = (long)bz * bsC;
#pragma unroll
    for (int mi = 0; mi < MI; ++mi) {
#pragma unroll
        for (int ni = 0; ni < 4; ++ni) {
            int row0 = m0 + rm + mi * 16 + cr;
            int col = n0 + wn * 64 + ni * 16 + cc;
            float bvl;
            long colterm;
            int md, rowstride;
            if (planeStride) {
                int plane = col >> 9;
                int c2 = col & 511;
                const float* bp = (plane == 0) ? b0 : ((plane == 1) ? b1 : b2);
                bvl = bp[c2];
                md = (modes >> (2 * plane)) & 3;
                colterm = (long)plane * planeStride + c2;
                rowstride = 512;
            } else {
                bvl = b0 ? b0[col] : 0.0f;
                md = modes & 3;
                colterm = col;
                rowstride = N;
            }
#pragma unroll
            for (int r = 0; r < 4; ++r) {
                float v = acc[mi][ni][r] + bvl;
                if (md == 1) v = 1.0f / (1.0f + __expf(-v));
                else if (md == 2) v = gelu_f(v);
                long idx;
                if (PCK) idx = cbase + poff(row0 + r, col, N);
                else     idx = cbase + (long)(row0 + r) * rowstride + colterm;
                if (resf) v += resf[idx];
                if (resb) v += ldf(resb, idx);
                if (Cf) Cf[idx] = v;
                else Cb[idx] = __float2bfloat16(v);
            }
        }
    }
}

// ---------------- 8-phase 256x256 MFMA GEMM (T3+T4 template port) -----------------
// 8 waves (2M x 4N), BK=64, 128KB LDS = 2 K-tile buffers (even->buf0, odd->buf1).
// Phase: asm ds_read frags || stage-issue -> s_barrier -> lgkmcnt(0)+sched_barrier
// (rule 18) -> setprio(1)+16 MFMA -> [vmcnt(4) at odd-phase ends: counted, never 0
// in-loop] -> s_barrier. T2 swizzle baked into packed layout (R13: conflicts -> 0).
// EPI 0: Cb packed + bias b0 + gelu (s7).  EPI 1: fused-Yt into yq (s4).
// EPI 2: 3x512-col planes, per-plane bias b0/b1/b2, sigmoid on plane 2, linear
//        write Cb + plane*planeStride (s2). 256-tile never straddles a plane? It
//        does per-ni (col span 16) — plane computed per-element-col, same as the
//        proven 2-phase plane path.
#define PH_BAR  __builtin_amdgcn_s_barrier()
#define PH_LGKM do { asm volatile("s_waitcnt lgkmcnt(0)" ::: "memory");      \
                     __builtin_amdgcn_sched_barrier(0); } while (0)
#define GATE4   asm volatile("s_waitcnt vmcnt(4)" ::: "memory")
#define MMA4(MH)                                                             \
    do {                                                                     \
        __builtin_amdgcn_s_setprio(1);                                       \
        _Pragma("unroll") for (int j = 0; j < 4; ++j) {                      \
            _Pragma("unroll") for (int ni = 0; ni < 4; ++ni)                 \
                acc[(MH) * 4 + j][ni] =                                      \
                    __builtin_amdgcn_mfma_f32_16x16x32_bf16(                 \
                        af[j], bv[ni], acc[(MH) * 4 + j][ni], 0, 0, 0);      \
        }                                                                    \
        __builtin_amdgcn_s_setprio(0);                                       \
    } while (0)

template <int EPI>
__global__ __launch_bounds__(512, 2) void mfma_gemm8(
    const bf16* __restrict__ A, const bf16* __restrict__ Bt,
    const float* __restrict__ b0, const float* __restrict__ b1,
    const float* __restrict__ b2,
    bf16* __restrict__ Cb, bf16* __restrict__ yq,
    int M, int N, int K, long bsB, long planeStride) {
    __shared__ short Sh[65536];  // 128 KB
    int tid = threadIdx.x;
    int lane = tid & 63, w = tid >> 6;   // wave 0..7
    int wm = w >> 2, wn = w & 3;
    int fr = lane & 15;

    // 3D chunked XCD swizzle (nwg % 8 == 0 for all users: 256/384/512 blocks)
    int gx = gridDim.x, gy = gridDim.y;
    long nwg = (long)gx * gy * gridDim.z;
    long o = blockIdx.x + (long)gx * (blockIdx.y + (long)gy * blockIdx.z);
    long wk = (o & 7) * (nwg >> 3) + (o >> 3);
    int bx = (int)(wk % gx);
    long rq = wk / gx;
    int by = (int)(rq % gy);
    int bz = (int)(rq / gy);
    int m0 = by * 256, n0 = bx * 256;

    const short* Ag = (const short*)A;
    const short* Bg = (const short*)Bt + (long)bz * bsB;
    int kt32 = K >> 5;

    // stage pointers: wave w stages strips 2w, 2w+1
    const short* sA0 = Ag + (long)((m0 >> 4) + 2 * w) * kt32 * 512 + lane * 8;
    const short* sA1 = sA0 + (long)kt32 * 512;
    const short* sB0 = Bg + (long)((n0 >> 4) + 2 * w) * kt32 * 512 + lane * 8;
    const short* sB1 = sB0 + (long)kt32 * 512;
    short* dA0 = Sh + ((2 * w) >> 3) * 8192 + ((2 * w) & 7) * 1024;
    short* dA1 = Sh + ((2 * w + 1) >> 3) * 8192 + ((2 * w + 1) & 7) * 1024;
    short* dB0 = dA0 + 16384;
    short* dB1 = dA1 + 16384;
    auto stageA = [&](int t, int kk) {
        long so = (long)(t * 2 + kk) * 512;
        int dof = (t & 1) * 32768 + kk * 512;
        GLD16(sA0 + so, dA0 + dof);
        GLD16(sA1 + so, dA1 + dof);
    };
    auto stageB = [&](int t, int kk) {
        long so = (long)(t * 2 + kk) * 512;
        int dof = (t & 1) * 32768 + kk * 512;
        GLD16(sB0 + so, dB0 + dof);
        GLD16(sB1 + so, dB1 + dof);
    };

    // fragment read bases (bytes): T2-swizzled granule (matches poff producer)
    int gsw = ((lane >> 4) ^ ((fr >> 1) & 3)) * 16;
    unsigned aBase = lds_off(Sh) + wm * 16384 + fr * 64 + gsw;
    unsigned bBase = lds_off(Sh) + 32768 + (wn >> 1) * 16384 + (wn & 1) * 8192 +
                     fr * 64 + gsw;
    unsigned aB00 = aBase, aB01 = aBase + 1024, aB10 = aBase + 65536, aB11 = aBase + 66560;
    unsigned bB00 = bBase, bB01 = bBase + 1024, bB10 = bBase + 65536, bB11 = bBase + 66560;

    f32x4 acc[8][4];
    f32x4 zz = {0.f, 0.f, 0.f, 0.f};
#pragma unroll
    for (int i = 0; i < 8; ++i)
#pragma unroll
        for (int j = 0; j < 4; ++j) acc[i][j] = zz;
    bf16x8 af[4], bv[4];

    auto rdA_lo = [&](unsigned b) {
        DSR(af[0], b, 0); DSR(af[1], b, 2048); DSR(af[2], b, 4096); DSR(af[3], b, 6144);
    };
    auto rdA_hi = [&](unsigned b) {
        DSR(af[0], b, 8192); DSR(af[1], b, 10240); DSR(af[2], b, 12288); DSR(af[3], b, 14336);
    };
    auto rdB = [&](unsigned b) {
        DSR(bv[0], b, 0); DSR(bv[1], b, 2048); DSR(bv[2], b, 4096); DSR(bv[3], b, 6144);
    };

    // prologue: tile 0 (A kk0, B kk0, A kk1, B kk1); gate: 4 oldest landed
    stageA(0, 0); stageB(0, 0); stageA(0, 1); stageB(0, 1);
    asm volatile("s_waitcnt vmcnt(4)" ::: "memory");
    PH_BAR;

    int nkt = K >> 6;
    int niter = nkt >> 1;
#pragma unroll 1
    for (int i = 0; i < niter; ++i) {
        int t1 = 2 * i + 1, t2 = 2 * i + 2;
        bool st2 = t2 < nkt;
        // ph0: tile 2i, kk0, mh0
        rdB(bB00); rdA_lo(aB00);
        stageA(t1, 0);
        PH_BAR; PH_LGKM; MMA4(0); PH_BAR;
        // ph1: kk0, mh1 (bv reused)
        rdA_hi(aB00);
        stageB(t1, 0);
        PH_BAR; PH_LGKM; MMA4(1); GATE4; PH_BAR;
        // ph2: kk1, mh0
        rdB(bB01); rdA_lo(aB01);
        stageA(t1, 1);
        PH_BAR; PH_LGKM; MMA4(0); PH_BAR;
        // ph3: kk1, mh1
        rdA_hi(aB01);
        stageB(t1, 1);
        PH_BAR; PH_LGKM; MMA4(1); GATE4; PH_BAR;
        // ph4: tile 2i+1, kk0, mh0
        rdB(bB10); rdA_lo(aB10);
        if (st2) stageA(t2, 0);
        PH_BAR; PH_LGKM; MMA4(0); PH_BAR;
        // ph5
        rdA_hi(aB10);
        if (st2) stageB(t2, 0);
        PH_BAR; PH_LGKM; MMA4(1); GATE4; PH_BAR;
        // ph6: kk1, mh0
        rdB(bB11); rdA_lo(aB11);
        if (st2) stageA(t2, 1);
        PH_BAR; PH_LGKM; MMA4(0); PH_BAR;
        // ph7
        rdA_hi(aB11);
        if (st2) stageB(t2, 1);
        PH_BAR; PH_LGKM; MMA4(1); GATE4; PH_BAR;
    }

    int cc = lane & 15, cr = (lane >> 4) * 4;
    if (EPI == 1) {
        // fused-Yt: 16-col num/den interleaved B; all lanes active
        long qb = (long)bz * (long)(T_ * D_);
        int dbase = (n0 + wn * 64) >> 1;
#pragma unroll
        for (int mi = 0; mi < 8; ++mi) {
            int row0 = m0 + wm * 128 + mi * 16 + cr;
#pragma unroll
            for (int pp = 0; pp < 2; ++pp) {
                int d = dbase + pp * 16 + cc;
#pragma unroll
                for (int r = 0; r < 4; ++r) {
                    long qi = qb + (long)(row0 + r) * D_ + d;
                    float sq = ldf((const bf16*)yq, qi);
                    yq[qi] = __float2bfloat16(sq * acc[mi][2 * pp][r] /
                                              acc[mi][2 * pp + 1][r]);
                }
            }
        }
    } else if (EPI == 2) {
        // 3-plane linear write (s2): bias per plane; sigmoid on plane 2 (sigQ)
#pragma unroll
        for (int mi = 0; mi < 8; ++mi) {
            int row0 = m0 + wm * 128 + mi * 16 + cr;
#pragma unroll
            for (int ni = 0; ni < 4; ++ni) {
                int col = n0 + wn * 64 + ni * 16 + cc;
                int plane = col >> 9;
                int c2 = col & 511;
                const float* bp = (plane == 0) ? b0 : ((plane == 1) ? b1 : b2);
                float bvl = bp[c2];
                long pbase = (long)plane * planeStride;
#pragma unroll
                for (int r = 0; r < 4; ++r) {
                    float v = acc[mi][ni][r] + bvl;
                    if (plane == 2) v = 1.0f / (1.0f + __expf(-v));
                    Cb[pbase + (long)(row0 + r) * 512 + c2] = __float2bfloat16(v);
                }
            }
        }
    } else {
        // packed C write + bias + gelu (s7)
#pragma unroll
        for (int mi = 0; mi < 8; ++mi) {
            int row0 = m0 + wm * 128 + mi * 16 + cr;
#pragma unroll
            for (int ni = 0; ni < 4; ++ni) {
                int col = n0 + wn * 64 + ni * 16 + cc;
                float bvl = b0[col];
#pragma unroll
                for (int r = 0; r < 4; ++r) {
                    float v = gelu_f(acc[mi][ni][r] + bvl);
                    Cb[poff(row0 + r, col, N)] = __float2bfloat16(v);
                }
            }
        }
    }
}

extern "C" void kernel_launch(void* const* d_in, const int* in_sizes, int n_in,
                              void* d_out, int out_size, void* d_ws, size_t ws_size,
                              hipStream_t stream) {
    const float* x    = (const float*)d_in[0];
    const float* ln1g = (const float*)d_in[1];
    const float* ln1b = (const float*)d_in[2];
    const float* Wk   = (const float*)d_in[3];
    const float* bk   = (const float*)d_in[4];
    const float* Wv   = (const float*)d_in[5];
    const float* bv   = (const float*)d_in[6];
    const float* Wq   = (const float*)d_in[7];
    const float* bq   = (const float*)d_in[8];
    const float* w    = (const float*)d_in[9];
    const float* Wo   = (const float*)d_in[10];
    const float* bo   = (const float*)d_in[11];
    const float* ln2g = (const float*)d_in[12];
    const float* ln2b = (const float*)d_in[13];
    const float* W1   = (const float*)d_in[14];
    const float* b1   = (const float*)d_in[15];
    const float* W2   = (const float*)d_in[16];
    const float* b2   = (const float*)d_in[17];
    float* out = (float*)d_out;

    const long S_BTD = (long)B_ * T_ * D_;      // 8,388,608
    const long S_TD  = (long)T_ * D_;           // 1,048,576
    const long S_TT  = (long)T_ * T_;           // 4,194,304
    const long S_B2D = (long)B_ * T_ * 2 * D_;  // 16,777,216
    const long S_DD  = (long)D_ * D_;           // 262,144

    bf16* h1     = (bf16*)d_ws;            // later h2 (both PACKED)
    bf16* outres = h1 + S_BTD;             // linear
    bf16* ew     = outres + S_BTD;         // PACKED
    bf16* KVQ    = ew + S_TT;              // K|V|Q planes (3*S_BTD), linear
    bf16* kv2t   = KVQ + 3 * S_BTD;        // S_B2D, PACKED+interleaved per batch
    bf16* mk     = kv2t + S_B2D;           // S_TD bf16
    bf16* WkT    = mk + 2 * S_TD;          // all weights PACKED
    bf16* WvT    = WkT + S_DD;
    bf16* WqT    = WvT + S_DD;
    bf16* WoT    = WqT + S_DD;
    bf16* W1T    = WoT + S_DD;             // [H,D]
    bf16* W2T    = W1T + (long)D_ * H_;    // [D,H]
    bf16* Kb  = KVQ;
    bf16* Vb  = KVQ + S_BTD;
    bf16* Qb  = KVQ + 2 * S_BTD;           // sigQ linear, then Yt in place (s4)
    bf16* hH  = KVQ;                       // PACKED; spans K|V planes (dead) + more
    bf16* h2  = h1;

    const int M = B_ * T_;  // 16384

    WT6 p;
    p.src[0] = Wk; p.src[1] = Wv; p.src[2] = Wq; p.src[3] = Wo; p.src[4] = W1; p.src[5] = W2;
    p.dst[0] = WkT; p.dst[1] = WvT; p.dst[2] = WqT; p.dst[3] = WoT; p.dst[4] = W1T; p.dst[5] = W2T;
    p.K[0] = p.K[1] = p.K[2] = p.K[3] = 512; p.K[4] = 512; p.K[5] = 2048;
    p.N[0] = p.N[1] = p.N[2] = p.N[3] = 512; p.N[4] = 2048; p.N[5] = 512;

    // 1. PREP: wtrans(6) + LN1 + expw in ONE launch
    prep_kernel<<<6144 + 16384 + 2048, 256, 0, stream>>>(p, x, ln1g, ln1b, h1, w, ew);
    // 2. K|V|sigQ GEMM (8-phase, EPI=2): planes linear -> Kb,Vb,Qb
    mfma_gemm8<2><<<dim3(1536 / 256, M / 256, 1), 512, 0, stream>>>(
        h1, WkT, bk, bv, bq, Kb, nullptr, M, 1536, D_, 0, S_BTD);
    // 3a. mk = max_b K; 3b. kv2t packed + 16-col interleave
    maxk_kernel<<<S_TD / 256, 256, 0, stream>>>(Kb, mk);
    kv2t_kernel<<<dim3(T_ / 64, D_ / 64, B_), 256, 0, stream>>>(Kb, Vb, mk, kv2t);
    // 4. FUSED s4 (8-phase, EPI=1): Yt = sigQ*(ew@expK*V)/(ew@expK) in place into Qb
    mfma_gemm8<1><<<dim3(1024 / 256, T_ / 256, B_), 512, 0, stream>>>(
        ew, kv2t, nullptr, nullptr, nullptr, nullptr, Qb, T_, 1024, T_,
        (long)1024 * T_, 0);
    // 5. out = Yt@Wo + bo + x, C linear + f32 residual (2-phase)
    mfma_gemm<128, 2><<<dim3(D_ / 128, M / 128, 1), 256, 0, stream>>>(
        Qb, WoT, bo, nullptr, nullptr, outres, nullptr, nullptr, x, nullptr,
        M, D_, D_, 0, 0, 0, 0);
    // 6. h2 = LN2(out), packed
    ln_kernel<bf16, true><<<M, 256, 0, stream>>>(outres, ln2g, ln2b, h2);
    // 7. hH = gelu(h2@W1 + b1) (8-phase, EPI=0), C PACKED (= step-8 A)
    mfma_gemm8<0><<<dim3(H_ / 256, M / 256, 1), 512, 0, stream>>>(
        h2, W1T, b1, nullptr, nullptr, hH, nullptr, M, H_, D_, 0, 0);
    // 8. y = gelu(hH@W2 + b2) + out -> f32 d_out (2-phase)
    mfma_gemm<128, 3><<<dim3(D_ / 128, M / 128, 1), 256, 0, stream>>>(
        hH, W2T, b2, nullptr, nullptr, nullptr, out, outres, nullptr, nullptr,
        M, D_, H_, 2, 0, 0, 0);
}